// Round 1
// baseline (1221.154 us; speedup 1.0000x reference)
//
#include <hip/hip_runtime.h>
#include <hip/hip_bf16.h>
#include <math.h>

#define B_    32
#define S_    512
#define DIM_  1024
#define HID_  4096
#define E_    8
#define TOPK_ 2
#define CAP_  8
#define NSLOT_ 64

typedef __bf16 bf16_t;
typedef bf16_t bf16x8 __attribute__((ext_vector_type(8)));
typedef float  f32x4  __attribute__((ext_vector_type(4)));

__device__ __forceinline__ ushort f2bf(float f) {
    union { float f; unsigned u; } v; v.f = f;
    unsigned r = (v.u + 0x7fffu + ((v.u >> 16) & 1u)) >> 16;
    return (ushort)r;
}

// ---------------- router ----------------
__global__ void k_mean(const float* __restrict__ rin, float* __restrict__ ri) {
    int b = blockIdx.x;
    int d4 = threadIdx.x;                       // 256 threads x float4 = 1024 dims
    const float4* p = (const float4*)(rin + (size_t)b * S_ * DIM_) + d4;
    float4 acc = {0.f, 0.f, 0.f, 0.f};
    for (int s = 0; s < S_; ++s) {
        float4 v = p[(size_t)s * (DIM_ / 4)];
        acc.x += v.x; acc.y += v.y; acc.z += v.z; acc.w += v.w;
    }
    const float inv = 1.0f / (float)S_;
    float4 o = {acc.x * inv, acc.y * inv, acc.z * inv, acc.w * inv};
    ((float4*)(ri + (size_t)b * DIM_))[d4] = o;
}

__global__ void k_router(const float* __restrict__ ri, const float* __restrict__ noise,
                         const float* __restrict__ Wg, const float* __restrict__ bg,
                         const float* __restrict__ Wn, const float* __restrict__ bn,
                         int* __restrict__ slot_sample, float* __restrict__ slot_gate) {
    __shared__ float noisy[B_][E_];
    __shared__ int   top_i[B_][TOPK_];
    __shared__ float top_g[B_][TOPK_];
    int t = threadIdx.x;                 // 256 = 32 samples x 8 experts
    int b = t >> 3, e = t & 7;
    {
        float accg = 0.f, accn = 0.f;
        const float* r = ri + (size_t)b * DIM_;
        for (int d = 0; d < DIM_; ++d) {
            float rv = r[d];
            accg += rv * Wg[d * E_ + e];
            accn += rv * Wn[d * E_ + e];
        }
        accg += bg[e]; accn += bn[e];
        float sp = (accn > 20.f) ? accn : log1pf(expf(accn));   // softplus
        noisy[b][e] = accg + noise[b * E_ + e] * sp;
    }
    __syncthreads();
    if (t < B_) {
        float v1 = -INFINITY, v2 = -INFINITY; int i1 = 0, i2 = 0;
        for (int ee = 0; ee < E_; ++ee) {
            float v = noisy[t][ee];
            if (v > v1)      { v2 = v1; i2 = i1; v1 = v; i1 = ee; }
            else if (v > v2) { v2 = v; i2 = ee; }
        }
        float g2 = expf(v2 - v1);
        float s = 1.f + g2;
        top_i[t][0] = i1; top_i[t][1] = i2;
        top_g[t][0] = 1.f / s; top_g[t][1] = g2 / s;
    }
    if (t < NSLOT_) { slot_sample[t] = -1; slot_gate[t] = 0.f; }
    __syncthreads();
    if (t == 0) {
        int cnt[E_];
        for (int ee = 0; ee < E_; ++ee) cnt[ee] = 0;
        for (int p = 0; p < B_ * TOPK_; ++p) {       // flat order == stable sort order
            int bb = p >> 1, kk = p & 1;
            int ee = top_i[bb][kk];
            int c = cnt[ee]++;
            if (c < CAP_) {
                slot_sample[ee * CAP_ + c] = bb;
                slot_gate[ee * CAP_ + c]   = top_g[bb][kk];
            }
        }
    }
}

// ---------------- conversions ----------------
__global__ void k_cvt_x(const float* __restrict__ x, ushort* __restrict__ xb, int n8) {
    int i = blockIdx.x * blockDim.x + threadIdx.x;   // 8 elements each
    if (i >= n8) return;
    const float4* p = (const float4*)x + (size_t)i * 2;
    float4 a = p[0], b = p[1];
    union { ushort s[8]; uint4 v; } u;
    u.s[0] = f2bf(a.x); u.s[1] = f2bf(a.y); u.s[2] = f2bf(a.z); u.s[3] = f2bf(a.w);
    u.s[4] = f2bf(b.x); u.s[5] = f2bf(b.y); u.s[6] = f2bf(b.z); u.s[7] = f2bf(b.w);
    ((uint4*)xb)[i] = u.v;
}

// W [K][N] fp32 -> Wt [N][K] bf16 (per expert in blockIdx.z)
__global__ void k_transpose_cvt(const float* __restrict__ W, ushort* __restrict__ Wt,
                                int K, int N) {
    __shared__ float tile[64][65];
    size_t eoff = (size_t)blockIdx.z * K * N;
    const float* Win = W + eoff;
    ushort* Wout = Wt + eoff;
    int n0 = blockIdx.x * 64, k0 = blockIdx.y * 64;
    int t = threadIdx.x;
    int r = t >> 4;             // 0..15
    int c4 = (t & 15) << 2;     // 0..60
#pragma unroll
    for (int i = 0; i < 4; ++i) {
        float4 v = *(const float4*)(Win + (size_t)(k0 + r + i * 16) * N + n0 + c4);
        tile[r + i * 16][c4 + 0] = v.x;
        tile[r + i * 16][c4 + 1] = v.y;
        tile[r + i * 16][c4 + 2] = v.z;
        tile[r + i * 16][c4 + 3] = v.w;
    }
    __syncthreads();
#pragma unroll
    for (int i = 0; i < 4; ++i) {
        int nn = r + i * 16;
        ushort4 o;
        o.x = f2bf(tile[c4 + 0][nn]);
        o.y = f2bf(tile[c4 + 1][nn]);
        o.z = f2bf(tile[c4 + 2][nn]);
        o.w = f2bf(tile[c4 + 3][nn]);
        *(ushort4*)(Wout + (size_t)(n0 + nn) * K + k0 + c4) = o;
    }
}

// ---------------- GEMM mainloop (128x128 tile, BK=32, 4 waves) ----------------
// A: [128 rows][K] row-major bf16 (ushort), B: [128 cols][K] row-major (i.e. B^T)
#define LDSP 40   // 32 + 8 pad
__device__ __forceinline__ void gemm_mainloop(
    const ushort* __restrict__ Abase, int lda,
    const ushort* __restrict__ Bbase, int ldb,
    int K, ushort* lds_a, ushort* lds_b, f32x4 acc[4][4]) {
    int tid = threadIdx.x;
    int wave = tid >> 6, lane = tid & 63;
    int wm = wave & 1, wn = wave >> 1;
    int quad = lane >> 4, mr = lane & 15;
    int c0 = tid, c1 = tid + 256;
    int r0 = c0 >> 2, p0 = (c0 & 3) << 3;
    int r1 = c1 >> 2, p1 = (c1 & 3) << 3;
    for (int k0 = 0; k0 < K; k0 += 32) {
        uint4 a0 = *(const uint4*)(Abase + (size_t)r0 * lda + k0 + p0);
        uint4 a1 = *(const uint4*)(Abase + (size_t)r1 * lda + k0 + p1);
        uint4 b0 = *(const uint4*)(Bbase + (size_t)r0 * ldb + k0 + p0);
        uint4 b1 = *(const uint4*)(Bbase + (size_t)r1 * ldb + k0 + p1);
        __syncthreads();
        *(uint4*)&lds_a[r0 * LDSP + p0] = a0;
        *(uint4*)&lds_a[r1 * LDSP + p1] = a1;
        *(uint4*)&lds_b[r0 * LDSP + p0] = b0;
        *(uint4*)&lds_b[r1 * LDSP + p1] = b1;
        __syncthreads();
        bf16x8 af[4], bfr[4];
#pragma unroll
        for (int i = 0; i < 4; ++i)
            af[i] = *(const bf16x8*)&lds_a[(wm * 64 + i * 16 + mr) * LDSP + quad * 8];
#pragma unroll
        for (int i = 0; i < 4; ++i)
            bfr[i] = *(const bf16x8*)&lds_b[(wn * 64 + i * 16 + mr) * LDSP + quad * 8];
#pragma unroll
        for (int i = 0; i < 4; ++i)
#pragma unroll
            for (int j = 0; j < 4; ++j)
                acc[i][j] = __builtin_amdgcn_mfma_f32_16x16x32_bf16(af[i], bfr[j], acc[i][j], 0, 0, 0);
    }
}

__global__ __launch_bounds__(256, 2) void k_gemm1(
    const ushort* __restrict__ xb, const ushort* __restrict__ w1t,
    const float* __restrict__ b1, const int* __restrict__ slot_sample,
    ushort* __restrict__ H) {
    __shared__ ushort As[128 * LDSP];
    __shared__ ushort Bs[128 * LDSP];
    int slot = blockIdx.z;
    int samp = slot_sample[slot];
    if (samp < 0) return;
    int e = slot >> 3;
    int mt = blockIdx.y, nt = blockIdx.x;
    const ushort* Abase = xb + ((size_t)samp * S_ + mt * 128) * DIM_;
    const ushort* Bbase = w1t + (size_t)e * HID_ * DIM_ + (size_t)(nt * 128) * DIM_;
    f32x4 acc[4][4];
#pragma unroll
    for (int i = 0; i < 4; ++i)
#pragma unroll
        for (int j = 0; j < 4; ++j) acc[i][j] = (f32x4){0.f, 0.f, 0.f, 0.f};
    gemm_mainloop(Abase, DIM_, Bbase, DIM_, DIM_, As, Bs, acc);
    int wave = threadIdx.x >> 6, lane = threadIdx.x & 63;
    int wm = wave & 1, wn = wave >> 1, quad = lane >> 4, mr = lane & 15;
    ushort* Hrow = H + ((size_t)slot * S_ + mt * 128) * HID_ + nt * 128;
#pragma unroll
    for (int j = 0; j < 4; ++j) {
        int nl = wn * 64 + j * 16 + mr;
        float bias = b1[e * HID_ + nt * 128 + nl];
#pragma unroll
        for (int i = 0; i < 4; ++i) {
#pragma unroll
            for (int r = 0; r < 4; ++r) {
                int ml = wm * 64 + i * 16 + quad * 4 + r;
                float v = acc[i][j][r] + bias;
                float g = 0.5f * v * (1.0f + erff(v * 0.70710678118654752f));
                Hrow[(size_t)ml * HID_ + nl] = f2bf(g);
            }
        }
    }
}

__global__ __launch_bounds__(256, 2) void k_gemm2(
    const ushort* __restrict__ H, const ushort* __restrict__ w2t,
    const float* __restrict__ b2, const int* __restrict__ slot_sample,
    const float* __restrict__ slot_gate, float* __restrict__ out) {
    __shared__ ushort As[128 * LDSP];
    __shared__ ushort Bs[128 * LDSP];
    int slot = blockIdx.z;
    int samp = slot_sample[slot];
    if (samp < 0) return;
    int e = slot >> 3;
    float gate = slot_gate[slot];
    int mt = blockIdx.y, nt = blockIdx.x;
    const ushort* Abase = H + ((size_t)slot * S_ + mt * 128) * HID_;
    const ushort* Bbase = w2t + (size_t)e * DIM_ * HID_ + (size_t)(nt * 128) * HID_;
    f32x4 acc[4][4];
#pragma unroll
    for (int i = 0; i < 4; ++i)
#pragma unroll
        for (int j = 0; j < 4; ++j) acc[i][j] = (f32x4){0.f, 0.f, 0.f, 0.f};
    gemm_mainloop(Abase, HID_, Bbase, HID_, HID_, As, Bs, acc);
    int wave = threadIdx.x >> 6, lane = threadIdx.x & 63;
    int wm = wave & 1, wn = wave >> 1, quad = lane >> 4, mr = lane & 15;
    float* Orow = out + ((size_t)samp * S_ + mt * 128) * DIM_ + nt * 128;
#pragma unroll
    for (int j = 0; j < 4; ++j) {
        int nl = wn * 64 + j * 16 + mr;
        float bias = b2[e * DIM_ + nt * 128 + nl];
#pragma unroll
        for (int i = 0; i < 4; ++i) {
#pragma unroll
            for (int r = 0; r < 4; ++r) {
                int ml = wm * 64 + i * 16 + quad * 4 + r;
                float v = acc[i][j][r] + bias;
                atomicAdd(&Orow[(size_t)ml * DIM_ + nl], v * gate);
            }
        }
    }
}

// ---------------- launch ----------------
extern "C" void kernel_launch(void* const* d_in, const int* in_sizes, int n_in,
                              void* d_out, int out_size, void* d_ws, size_t ws_size,
                              hipStream_t stream) {
    const float* rin   = (const float*)d_in[0];
    const float* x     = (const float*)d_in[1];
    const float* noise = (const float*)d_in[2];
    const float* Wg    = (const float*)d_in[3];
    const float* bg    = (const float*)d_in[4];
    const float* Wn    = (const float*)d_in[5];
    const float* bn    = (const float*)d_in[6];
    const float* W1    = (const float*)d_in[7];
    const float* b1    = (const float*)d_in[8];
    const float* W2    = (const float*)d_in[9];
    const float* b2    = (const float*)d_in[10];
    float* out = (float*)d_out;

    char* ws = (char*)d_ws;
    float*  ri          = (float*)ws;                         // 131072 B
    int*    slot_sample = (int*)(ws + 131072);                // 256 B
    float*  slot_gate   = (float*)(ws + 131072 + 256);        // 256 B
    ushort* xb  = (ushort*)(ws + 135168);                     // 32 MB
    ushort* w1t = (ushort*)(ws + 135168 + 33554432);          // 64 MB
    ushort* w2t = (ushort*)(ws + 135168 + 33554432 + 67108864);   // 64 MB
    ushort* H   = (ushort*)(ws + 135168 + 33554432 + 2 * 67108864); // 256 MB

    hipMemsetAsync(d_out, 0, (size_t)out_size * sizeof(float), stream);
    k_mean<<<B_, 256, 0, stream>>>(rin, ri);
    k_router<<<1, 256, 0, stream>>>(ri, noise, Wg, bg, Wn, bn, slot_sample, slot_gate);
    k_cvt_x<<<(B_ * S_ * DIM_ / 8 + 255) / 256, 256, 0, stream>>>(x, xb, B_ * S_ * DIM_ / 8);
    k_transpose_cvt<<<dim3(HID_ / 64, DIM_ / 64, E_), 256, 0, stream>>>(W1, w1t, DIM_, HID_);
    k_transpose_cvt<<<dim3(DIM_ / 64, HID_ / 64, E_), 256, 0, stream>>>(W2, w2t, HID_, DIM_);
    k_gemm1<<<dim3(HID_ / 128, S_ / 128, NSLOT_), 256, 0, stream>>>(xb, w1t, b1, slot_sample, H);
    k_gemm2<<<dim3(DIM_ / 128, S_ / 128, NSLOT_), 256, 0, stream>>>(H, w2t, b2, slot_sample, slot_gate, out);
}

// Round 2
// 1190.109 us; speedup vs baseline: 1.0261x; 1.0261x over previous
//
#include <hip/hip_runtime.h>
#include <hip/hip_bf16.h>
#include <math.h>

#define B_    32
#define S_    512
#define DIM_  1024
#define HID_  4096
#define E_    8
#define TOPK_ 2
#define CAP_  8
#define NSLOT_ 64

typedef __bf16 bf16_t;
typedef bf16_t bf16x8 __attribute__((ext_vector_type(8)));
typedef float  f32x4  __attribute__((ext_vector_type(4)));

__device__ __forceinline__ ushort f2bf(float f) {
    union { float f; unsigned u; } v; v.f = f;
    unsigned r = (v.u + 0x7fffu + ((v.u >> 16) & 1u)) >> 16;
    return (ushort)r;
}

// async global->LDS, 16B per lane; LDS dest is wave-uniform base + lane*16
__device__ __forceinline__ void async_cp16(const ushort* g, ushort* l) {
    __builtin_amdgcn_global_load_lds(
        (const __attribute__((address_space(1))) unsigned int*)g,
        (__attribute__((address_space(3))) unsigned int*)l, 16, 0, 0);
}

// ---------------- router ----------------
__global__ void k_mean(const float* __restrict__ rin, float* __restrict__ ri) {
    int b = blockIdx.x;
    int d4 = threadIdx.x;                       // 256 threads x float4 = 1024 dims
    const float4* p = (const float4*)(rin + (size_t)b * S_ * DIM_) + d4;
    float4 acc = {0.f, 0.f, 0.f, 0.f};
    for (int s = 0; s < S_; ++s) {
        float4 v = p[(size_t)s * (DIM_ / 4)];
        acc.x += v.x; acc.y += v.y; acc.z += v.z; acc.w += v.w;
    }
    const float inv = 1.0f / (float)S_;
    float4 o = {acc.x * inv, acc.y * inv, acc.z * inv, acc.w * inv};
    ((float4*)(ri + (size_t)b * DIM_))[d4] = o;
}

__global__ void k_router(const float* __restrict__ ri, const float* __restrict__ noise,
                         const float* __restrict__ Wg, const float* __restrict__ bg,
                         const float* __restrict__ Wn, const float* __restrict__ bn,
                         int* __restrict__ slot_sample, float* __restrict__ slot_gate) {
    __shared__ float noisy[B_][E_];
    __shared__ int   top_i[B_][TOPK_];
    __shared__ float top_g[B_][TOPK_];
    int t = threadIdx.x;                 // 256 = 32 samples x 8 experts
    int b = t >> 3, e = t & 7;
    {
        float accg = 0.f, accn = 0.f;
        const float* r = ri + (size_t)b * DIM_;
        for (int d = 0; d < DIM_; ++d) {
            float rv = r[d];
            accg += rv * Wg[d * E_ + e];
            accn += rv * Wn[d * E_ + e];
        }
        accg += bg[e]; accn += bn[e];
        float sp = (accn > 20.f) ? accn : log1pf(expf(accn));   // softplus
        noisy[b][e] = accg + noise[b * E_ + e] * sp;
    }
    __syncthreads();
    if (t < B_) {
        float v1 = -INFINITY, v2 = -INFINITY; int i1 = 0, i2 = 0;
        for (int ee = 0; ee < E_; ++ee) {
            float v = noisy[t][ee];
            if (v > v1)      { v2 = v1; i2 = i1; v1 = v; i1 = ee; }
            else if (v > v2) { v2 = v; i2 = ee; }
        }
        float g2 = expf(v2 - v1);
        float s = 1.f + g2;
        top_i[t][0] = i1; top_i[t][1] = i2;
        top_g[t][0] = 1.f / s; top_g[t][1] = g2 / s;
    }
    if (t < NSLOT_) { slot_sample[t] = -1; slot_gate[t] = 0.f; }
    __syncthreads();
    if (t == 0) {
        int cnt[E_];
        for (int ee = 0; ee < E_; ++ee) cnt[ee] = 0;
        for (int p = 0; p < B_ * TOPK_; ++p) {       // flat order == stable sort order
            int bb = p >> 1, kk = p & 1;
            int ee = top_i[bb][kk];
            int c = cnt[ee]++;
            if (c < CAP_) {
                slot_sample[ee * CAP_ + c] = bb;
                slot_gate[ee * CAP_ + c]   = top_g[bb][kk];
            }
        }
    }
}

// ---------------- conversions ----------------
__global__ void k_cvt_x(const float* __restrict__ x, ushort* __restrict__ xb, int n8) {
    int i = blockIdx.x * blockDim.x + threadIdx.x;   // 8 elements each
    if (i >= n8) return;
    const float4* p = (const float4*)x + (size_t)i * 2;
    float4 a = p[0], b = p[1];
    union { ushort s[8]; uint4 v; } u;
    u.s[0] = f2bf(a.x); u.s[1] = f2bf(a.y); u.s[2] = f2bf(a.z); u.s[3] = f2bf(a.w);
    u.s[4] = f2bf(b.x); u.s[5] = f2bf(b.y); u.s[6] = f2bf(b.z); u.s[7] = f2bf(b.w);
    ((uint4*)xb)[i] = u.v;
}

// W [K][N] fp32 -> Wt [N][K] bf16 (per expert in blockIdx.z)
__global__ void k_transpose_cvt(const float* __restrict__ W, ushort* __restrict__ Wt,
                                int K, int N) {
    __shared__ float tile[64][65];
    size_t eoff = (size_t)blockIdx.z * K * N;
    const float* Win = W + eoff;
    ushort* Wout = Wt + eoff;
    int n0 = blockIdx.x * 64, k0 = blockIdx.y * 64;
    int t = threadIdx.x;
    int r = t >> 4;             // 0..15
    int c4 = (t & 15) << 2;     // 0..60
#pragma unroll
    for (int i = 0; i < 4; ++i) {
        float4 v = *(const float4*)(Win + (size_t)(k0 + r + i * 16) * N + n0 + c4);
        tile[r + i * 16][c4 + 0] = v.x;
        tile[r + i * 16][c4 + 1] = v.y;
        tile[r + i * 16][c4 + 2] = v.z;
        tile[r + i * 16][c4 + 3] = v.w;
    }
    __syncthreads();
#pragma unroll
    for (int i = 0; i < 4; ++i) {
        int nn = r + i * 16;
        ushort4 o;
        o.x = f2bf(tile[c4 + 0][nn]);
        o.y = f2bf(tile[c4 + 1][nn]);
        o.z = f2bf(tile[c4 + 2][nn]);
        o.w = f2bf(tile[c4 + 3][nn]);
        *(ushort4*)(Wout + (size_t)(n0 + nn) * K + k0 + c4) = o;
    }
}

// ---------------- GEMM mainloop (m97 structure: 128x128 tile, BK=32, 4 waves,
// global_load_lds width=16 staging, unpadded [row][32] LDS layout) ----------------
__device__ __forceinline__ void gemm_mainloop(
    const ushort* __restrict__ Abase, int lda,
    const ushort* __restrict__ Bbase, int ldb,
    int K, ushort* lds_a, ushort* lds_b, f32x4 acc[4][4]) {
    int tid = threadIdx.x;
    int wave = tid >> 6, lane = tid & 63;
    int wm = wave & 1, wn = wave >> 1;
    int quad = lane >> 4, mr = lane & 15;
    // staging: wave w covers row-segments w and w+4 (16 rows x 32 k each = 1 KB)
    int r_lo = lane >> 2;            // 0..15 row within segment
    int kp   = (lane & 3) << 3;      // 0,8,16,24
    const ushort* a_g0 = Abase + (size_t)(wave * 16 + r_lo) * lda + kp;
    const ushort* a_g1 = Abase + (size_t)((wave + 4) * 16 + r_lo) * lda + kp;
    const ushort* b_g0 = Bbase + (size_t)(wave * 16 + r_lo) * ldb + kp;
    const ushort* b_g1 = Bbase + (size_t)((wave + 4) * 16 + r_lo) * ldb + kp;
    ushort* a_l0 = lds_a + wave * 512;           // wave-uniform LDS bases
    ushort* a_l1 = lds_a + (wave + 4) * 512;
    ushort* b_l0 = lds_b + wave * 512;
    ushort* b_l1 = lds_b + (wave + 4) * 512;
    for (int k0 = 0; k0 < K; k0 += 32) {
        __syncthreads();                          // prior iter's ds_reads done
        async_cp16(a_g0 + k0, a_l0);
        async_cp16(a_g1 + k0, a_l1);
        async_cp16(b_g0 + k0, b_l0);
        async_cp16(b_g1 + k0, b_l1);
        __syncthreads();                          // vmcnt(0) drain: tiles staged
        bf16x8 af[4], bfr[4];
#pragma unroll
        for (int i = 0; i < 4; ++i)
            af[i] = *(const bf16x8*)&lds_a[(wm * 64 + i * 16 + mr) * 32 + quad * 8];
#pragma unroll
        for (int i = 0; i < 4; ++i)
            bfr[i] = *(const bf16x8*)&lds_b[(wn * 64 + i * 16 + mr) * 32 + quad * 8];
#pragma unroll
        for (int i = 0; i < 4; ++i)
#pragma unroll
            for (int j = 0; j < 4; ++j)
                acc[i][j] = __builtin_amdgcn_mfma_f32_16x16x32_bf16(af[i], bfr[j], acc[i][j], 0, 0, 0);
    }
}

__global__ __launch_bounds__(256, 2) void k_gemm1(
    const ushort* __restrict__ xb, const ushort* __restrict__ w1t,
    const float* __restrict__ b1, const int* __restrict__ slot_sample,
    ushort* __restrict__ H) {
    __shared__ ushort As[128 * 32];
    __shared__ ushort Bs[128 * 32];
    int slot = blockIdx.z;
    int samp = slot_sample[slot];
    if (samp < 0) return;
    int e = slot >> 3;
    int mt = blockIdx.y, nt = blockIdx.x;
    const ushort* Abase = xb + ((size_t)samp * S_ + mt * 128) * DIM_;
    const ushort* Bbase = w1t + (size_t)e * HID_ * DIM_ + (size_t)(nt * 128) * DIM_;
    f32x4 acc[4][4];
#pragma unroll
    for (int i = 0; i < 4; ++i)
#pragma unroll
        for (int j = 0; j < 4; ++j) acc[i][j] = (f32x4){0.f, 0.f, 0.f, 0.f};
    gemm_mainloop(Abase, DIM_, Bbase, DIM_, DIM_, As, Bs, acc);
    int wave = threadIdx.x >> 6, lane = threadIdx.x & 63;
    int wm = wave & 1, wn = wave >> 1, quad = lane >> 4, mr = lane & 15;
    ushort* Hrow = H + ((size_t)slot * S_ + mt * 128) * HID_ + nt * 128;
#pragma unroll
    for (int j = 0; j < 4; ++j) {
        int nl = wn * 64 + j * 16 + mr;
        float bias = b1[e * HID_ + nt * 128 + nl];
#pragma unroll
        for (int i = 0; i < 4; ++i) {
#pragma unroll
            for (int r = 0; r < 4; ++r) {
                int ml = wm * 64 + i * 16 + quad * 4 + r;
                float v = acc[i][j][r] + bias;
                float g = 0.5f * v * (1.0f + erff(v * 0.70710678118654752f));
                Hrow[(size_t)ml * HID_ + nl] = f2bf(g);
            }
        }
    }
}

__global__ __launch_bounds__(256, 2) void k_gemm2(
    const ushort* __restrict__ H, const ushort* __restrict__ w2t,
    const float* __restrict__ b2, const int* __restrict__ slot_sample,
    const float* __restrict__ slot_gate, float* __restrict__ out) {
    __shared__ ushort As[128 * 32];
    __shared__ ushort Bs[128 * 32];
    int slot = blockIdx.z;
    int samp = slot_sample[slot];
    if (samp < 0) return;
    int e = slot >> 3;
    float gate = slot_gate[slot];
    int mt = blockIdx.y, nt = blockIdx.x;
    const ushort* Abase = H + ((size_t)slot * S_ + mt * 128) * HID_;
    const ushort* Bbase = w2t + (size_t)e * DIM_ * HID_ + (size_t)(nt * 128) * HID_;
    f32x4 acc[4][4];
#pragma unroll
    for (int i = 0; i < 4; ++i)
#pragma unroll
        for (int j = 0; j < 4; ++j) acc[i][j] = (f32x4){0.f, 0.f, 0.f, 0.f};
    gemm_mainloop(Abase, HID_, Bbase, HID_, HID_, As, Bs, acc);
    int wave = threadIdx.x >> 6, lane = threadIdx.x & 63;
    int wm = wave & 1, wn = wave >> 1, quad = lane >> 4, mr = lane & 15;
    float* Orow = out + ((size_t)samp * S_ + mt * 128) * DIM_ + nt * 128;
#pragma unroll
    for (int j = 0; j < 4; ++j) {
        int nl = wn * 64 + j * 16 + mr;
        float bias = b2[e * DIM_ + nt * 128 + nl];
#pragma unroll
        for (int i = 0; i < 4; ++i) {
#pragma unroll
            for (int r = 0; r < 4; ++r) {
                int ml = wm * 64 + i * 16 + quad * 4 + r;
                float v = acc[i][j][r] + bias;
                atomicAdd(&Orow[(size_t)ml * DIM_ + nl], v * gate);
            }
        }
    }
}

// ---------------- launch ----------------
extern "C" void kernel_launch(void* const* d_in, const int* in_sizes, int n_in,
                              void* d_out, int out_size, void* d_ws, size_t ws_size,
                              hipStream_t stream) {
    const float* rin   = (const float*)d_in[0];
    const float* x     = (const float*)d_in[1];
    const float* noise = (const float*)d_in[2];
    const float* Wg    = (const float*)d_in[3];
    const float* bg    = (const float*)d_in[4];
    const float* Wn    = (const float*)d_in[5];
    const float* bn    = (const float*)d_in[6];
    const float* W1    = (const float*)d_in[7];
    const float* b1    = (const float*)d_in[8];
    const float* W2    = (const float*)d_in[9];
    const float* b2    = (const float*)d_in[10];
    float* out = (float*)d_out;

    char* ws = (char*)d_ws;
    float*  ri          = (float*)ws;                         // 131072 B
    int*    slot_sample = (int*)(ws + 131072);                // 256 B
    float*  slot_gate   = (float*)(ws + 131072 + 256);        // 256 B
    ushort* xb  = (ushort*)(ws + 135168);                     // 32 MB
    ushort* w1t = (ushort*)(ws + 135168 + 33554432);          // 64 MB
    ushort* w2t = (ushort*)(ws + 135168 + 33554432 + 67108864);   // 64 MB
    ushort* H   = (ushort*)(ws + 135168 + 33554432 + 2 * 67108864); // 256 MB

    hipMemsetAsync(d_out, 0, (size_t)out_size * sizeof(float), stream);
    k_mean<<<B_, 256, 0, stream>>>(rin, ri);
    k_router<<<1, 256, 0, stream>>>(ri, noise, Wg, bg, Wn, bn, slot_sample, slot_gate);
    k_cvt_x<<<(B_ * S_ * DIM_ / 8 + 255) / 256, 256, 0, stream>>>(x, xb, B_ * S_ * DIM_ / 8);
    k_transpose_cvt<<<dim3(HID_ / 64, DIM_ / 64, E_), 256, 0, stream>>>(W1, w1t, DIM_, HID_);
    k_transpose_cvt<<<dim3(DIM_ / 64, HID_ / 64, E_), 256, 0, stream>>>(W2, w2t, HID_, DIM_);
    k_gemm1<<<dim3(HID_ / 128, S_ / 128, NSLOT_), 256, 0, stream>>>(xb, w1t, b1, slot_sample, H);
    k_gemm2<<<dim3(DIM_ / 128, S_ / 128, NSLOT_), 256, 0, stream>>>(H, w2t, b2, slot_sample, slot_gate, out);
}